// Round 6
// baseline (320.276 us; speedup 1.0000x reference)
//
#include <hip/hip_runtime.h>
#include <hip/hip_fp16.h>

#define B_    16
#define C_    256
#define HW_   4096
#define CHW_  1048576
#define N_    65536
#define K_    1024
#define FLT_BIG 3.402823466e38f
#define GAP_T  1.2e-4f   // ref fp32-quant floor 6.1e-5 + 6sigma fp16 score err ~3.1e-5 + key-pack 8e-6 + margin

typedef _Float16 half8 __attribute__((ext_vector_type(8)));
typedef float   float16 __attribute__((ext_vector_type(16)));

__device__ __forceinline__ unsigned umin_(unsigned a, unsigned b) { return a < b ? a : b; }
__device__ __forceinline__ unsigned umax_(unsigned a, unsigned b) { return a > b ? a : b; }

// ---------------------------------------------------------------------------
// s_z[n] numpy pairwise order (PASSED r2/r4 - do not touch)
// ---------------------------------------------------------------------------
__global__ void sz_kernel(const float* __restrict__ z, float* __restrict__ sz) {
#pragma clang fp contract(off)
    int n = blockIdx.x * 256 + threadIdx.x;
    const float* zp = z + (size_t)(n >> 12) * CHW_ + (n & 4095);
    float blk[2];
    for (int h = 0; h < 2; h++) {
        const float* p = zp + (size_t)(h * 128) * HW_;
        float r[8];
#pragma unroll
        for (int j = 0; j < 8; j++) { float v = p[(size_t)j * HW_]; r[j] = v * v; }
        for (int i = 8; i < 128; i += 8) {
#pragma unroll
            for (int j = 0; j < 8; j++) { float v = p[(size_t)(i + j) * HW_]; r[j] += v * v; }
        }
        blk[h] = ((r[0] + r[1]) + (r[2] + r[3])) + ((r[4] + r[5]) + (r[6] + r[7]));
    }
    sz[n] = blk[0] + blk[1];
}

// ---------------------------------------------------------------------------
// s_c[k] numpy pairwise order (PASSED r2/r4)
// ---------------------------------------------------------------------------
__global__ void sc_kernel(const float* __restrict__ cb, float* __restrict__ sc) {
#pragma clang fp contract(off)
    int k = blockIdx.x * 256 + threadIdx.x;
    const float* p0 = cb + (size_t)k * C_;
    float blk[2];
    for (int h = 0; h < 2; h++) {
        const float* p = p0 + h * 128;
        float r[8];
#pragma unroll
        for (int j = 0; j < 8; j++) { float v = p[j]; r[j] = v * v; }
        for (int i = 8; i < 128; i += 8) {
#pragma unroll
            for (int j = 0; j < 8; j++) { float v = p[i + j]; r[j] += v * v; }
        }
        blk[h] = ((r[0] + r[1]) + (r[2] + r[3])) + ((r[4] + r[5]) + (r[6] + r[7]));
    }
    sc[k] = blk[0] + blk[1];
}

// ---------------------------------------------------------------------------
// Prep: codebook -> fp16 (x1024 exact scale, avoids fp16 denormal band),
// A-fragment image per K-step.  Element: (kk*1024 + k)*16 + h*8 + j
// with channel c = kk*16 + h*8 + j.  512 KB, L2-resident.
// ---------------------------------------------------------------------------
__global__ void cbh_prep(const float* __restrict__ cb, unsigned short* __restrict__ cbh) {
    int k = blockIdx.x, c = threadIdx.x;
    float v = cb[(size_t)k * C_ + c] * 1024.0f;
    __half hv = __float2half_rn(v);
    size_t F = ((size_t)(c >> 4) * 1024 + k) * 16 + ((c >> 3) & 1) * 8 + (c & 7);
    cbh[F] = __half_as_ushort(hv);
}

// Prep: cbT[c][k] = cb[k][c] fp32 (refine's coalesced per-lane-k loads)
__global__ void cbT_prep(const float* __restrict__ cb, float* __restrict__ cbT) {
    int c = blockIdx.x, k = threadIdx.x;
    cbT[(size_t)c * K_ + k] = cb[(size_t)k * C_ + c];
}

// ---------------------------------------------------------------------------
// fp16 MFMA score kernel.  Block = 64 pixels, 256 thr (4 waves).
// Wave w covers codes chunk*256 + w*64 + mt*32 + (l&31), 4 chunks of 256.
// A-frags from global (L2) with depth-2 register prefetch - no in-loop
// barriers.  z tile fp16 in LDS, XOR-swizzled (conflict-free b128 reads).
// Scores shifted +0.25 (positive => uint-monotone); packed key =
// (asuint(s') & ~127) | (chunk<<5)|(mt<<4)|r  -> branchless top-2 via
// u32 min/max, first-index ties automatic.
// C/D: col(pixel)=lane&31, row(code)=(r&3)+8*(r>>2)+4*(lane>>5) [HW-verified].
// ---------------------------------------------------------------------------
__global__ __launch_bounds__(256, 4)
void score_kernel(const float* __restrict__ z, const unsigned short* __restrict__ cbh,
                  const float* __restrict__ sc,
                  float* __restrict__ s1o, float* __restrict__ s2o,
                  int* __restrict__ i1o) {
    __shared__ __align__(16) int zw[64 * 132];   // 64 px rows x 132 words (128 data + 4 pad), 33792 B
    __shared__ float scs[1024];                  // sc + 0.25, 4 KB
    __shared__ float ex[4 * 64 * 4];             // cross-wave merge, 4 KB

    int t = threadIdx.x;
    int w = t >> 6, l = t & 63;
    int n0 = blockIdx.x * 64;

    // stage shifted sc
    for (int i = t; i < 1024; i += 256) scs[i] = sc[i] + 0.25f;

    // stage z tile as packed fp16 pairs, XOR-swizzled 16B chunks.
    // thread (w,l): pixel px=l, channels [w*64, w*64+64)
    {
        int px = l;
        const float* zp = z + (size_t)(n0 >> 12) * CHW_ + (n0 & 4095) + px;
        int key = (px >> 3) & 3;
#pragma unroll 4
        for (int i = 0; i < 32; i++) {
            int widx = w * 32 + i;               // logical word in row [0,128)
            int c0 = widx * 2;
            float v0 = zp[(size_t)c0 * HW_];
            float v1 = zp[(size_t)(c0 + 1) * HW_];
            unsigned pk = (unsigned)__half_as_ushort(__float2half_rn(v0))
                        | ((unsigned)__half_as_ushort(__float2half_rn(v1)) << 16);
            int c16 = widx >> 2, rem = widx & 3;
            zw[px * 132 + (((c16 ^ key) << 2) | rem)] = pk;
        }
    }
    __syncthreads();

    unsigned b1[2] = { 0xFFFFFFFFu, 0xFFFFFFFFu };
    unsigned b2[2] = { 0xFFFFFFFFu, 0xFFFFFFFFu };

    // A-frag base (ushort index): code-in-chunk row = w*64 + mt*32 + (l&31)
    const unsigned short* ab = cbh + ((size_t)(w * 64 + (l & 31)) * 16 + (l >> 5) * 8);
    // step s (0..63): offset = (s&15)*16384 + (s>>4)*4096 ; mt stride 512
    short rowmap = (short)((l >> 5) << 2);       // +4*(lane>>5) in C/D rows
    half8 pf[2][2];
#pragma unroll
    for (int i = 0; i < 2; i++) {
        const unsigned short* s = ab + (i & 15) * 16384 + (i >> 4) * 4096;
        pf[i][0] = *(const half8*)(s);
        pf[i][1] = *(const half8*)(s + 512);
    }

    int bkey = ((l & 31) >> 3) & 3;
    int prow0 = (l & 31) * 132;

    for (int chunk = 0; chunk < 4; chunk++) {
        float16 acc[2][2];
#pragma unroll
        for (int mt = 0; mt < 2; mt++)
#pragma unroll
            for (int nt = 0; nt < 2; nt++)
#pragma unroll
                for (int r = 0; r < 16; r++) acc[mt][nt][r] = 0.f;

#pragma unroll
        for (int kk = 0; kk < 16; kk++) {
            int step = chunk * 16 + kk;
            int buf = step & 1;
            half8 a0 = pf[buf][0], a1 = pf[buf][1];
            int ns = step + 2; if (ns > 63) ns = 63;
            {
                const unsigned short* s = ab + (ns & 15) * 16384 + (ns >> 4) * 4096;
                pf[buf][0] = *(const half8*)(s);
                pf[buf][1] = *(const half8*)(s + 512);
            }
            half8 bz[2];
#pragma unroll
            for (int nt = 0; nt < 2; nt++) {
                int c16 = kk * 2 + (l >> 5);
                int word = (nt * 32 * 132 + prow0) + ((c16 ^ bkey) << 2);
                bz[nt] = *(const half8*)((const char*)zw + (size_t)word * 4);
            }
            acc[0][0] = __builtin_amdgcn_mfma_f32_32x32x16_f16(a0, bz[0], acc[0][0], 0, 0, 0);
            acc[0][1] = __builtin_amdgcn_mfma_f32_32x32x16_f16(a0, bz[1], acc[0][1], 0, 0, 0);
            acc[1][0] = __builtin_amdgcn_mfma_f32_32x32x16_f16(a1, bz[0], acc[1][0], 0, 0, 0);
            acc[1][1] = __builtin_amdgcn_mfma_f32_32x32x16_f16(a1, bz[1], acc[1][1], 0, 0, 0);
        }

        // fold into packed-key top-2 (s' = sc+0.25 - 2^-9*acc, positive)
#pragma unroll
        for (int mt = 0; mt < 2; mt++)
#pragma unroll
            for (int r = 0; r < 16; r++) {
                int scode = chunk * 256 + w * 64 + mt * 32
                          + (r & 3) + ((r >> 2) << 3) + rowmap;
                float sv = scs[scode];
                unsigned emb = (unsigned)((chunk << 5) | (mt << 4) | r);
#pragma unroll
                for (int nt = 0; nt < 2; nt++) {
                    float s = fmaf(-0.001953125f, acc[mt][nt][r], sv);
                    unsigned key = (__float_as_uint(s) & 0xFFFFFF80u) | emb;
                    b2[nt] = umin_(b2[nt], umax_(b1[nt], key));
                    b1[nt] = umin_(b1[nt], key);
                }
            }
    }

    // decode + lane-pair merge (l, l^32: same pixel, disjoint code rows)
#pragma unroll
    for (int nt = 0; nt < 2; nt++) {
        unsigned e1 = b1[nt] & 127u;
        float f1 = __uint_as_float(b1[nt] & 0xFFFFFF80u);
        float f2 = __uint_as_float(b2[nt] & 0xFFFFFF80u);
        int idx = (int)(e1 >> 5) * 256 + w * 64 + (int)((e1 >> 4) & 1) * 32
                + (int)(e1 & 3) + (int)(((e1 >> 2) & 3) << 3) + (int)rowmap;

        float of1 = __shfl_xor(f1, 32, 64);
        int   oi  = __shfl_xor(idx, 32, 64);
        float of2 = __shfl_xor(f2, 32, 64);
        if (of1 < f1 || (of1 == f1 && oi < idx)) {
            f2 = fminf(f1, of2); f1 = of1; idx = oi;
        } else {
            f2 = fminf(f2, of1);
        }

        if (l < 32) {
            int e = (w * 64 + nt * 32 + l) * 4;
            ex[e + 0] = f1;
            ex[e + 1] = f2;
            ((int*)ex)[e + 2] = idx;
        }
    }
    __syncthreads();
    if (t < 64) {
        float cb1 = FLT_BIG, cb2 = FLT_BIG; int cj1 = 0;
#pragma unroll
        for (int wv = 0; wv < 4; wv++) {
            int e = (wv * 64 + t) * 4;
            float nb1 = ex[e + 0];
            float nb2 = ex[e + 1];
            int   nj1 = ((int*)ex)[e + 2];
            if (nb1 < cb1 || (nb1 == cb1 && nj1 < cj1)) {
                cb2 = fminf(cb1, nb2); cb1 = nb1; cj1 = nj1;
            } else {
                cb2 = fminf(cb2, nb1);
            }
        }
        int n = n0 + t;
        s1o[n] = cb1; s2o[n] = cb2; i1o[n] = cj1;
    }
}

// ---------------------------------------------------------------------------
// Flag pass: commit clear winners; compact near-ties.
// ---------------------------------------------------------------------------
__global__ void flag_kernel(const float* __restrict__ s1, const float* __restrict__ s2,
                            const int* __restrict__ i1,
                            int* __restrict__ fidx, float* __restrict__ out_idx,
                            int* __restrict__ list, int* __restrict__ count) {
    int n = blockIdx.x * 256 + threadIdx.x;
    int j = i1[n];
    fidx[n] = j;
    out_idx[n] = (float)j;
    if (s2[n] - s1[n] < GAP_T) {
        int pos = atomicAdd(count, 1);
        list[pos] = n;
    }
}

// ---------------------------------------------------------------------------
// Exact refine (PASSED r4 semantics, unchanged except grid stride 8192):
// wave per flagged pixel, fp64 dot via cbT, then reference-quantized fp32:
//   dq = fp32( fp32(sz + sc[k]) - 2*fp32(dot) ), first-index argmin.
// Grid 2048 blocks -> 32 waves/CU -> L2 latency hidden.
// ---------------------------------------------------------------------------
__global__ void refine_kernel(const float* __restrict__ z, const float* __restrict__ cbT,
                              const float* __restrict__ sz, const float* __restrict__ sc,
                              const int* __restrict__ list, const int* __restrict__ count,
                              int* __restrict__ fidx, float* __restrict__ out_idx) {
    __shared__ double zd[4][256];
    int w = threadIdx.x >> 6, l = threadIdx.x & 63;
    int cnt = *count;
    if (cnt > 65536) cnt = 65536;
    for (int ii = blockIdx.x * 4 + w; ii < cnt; ii += 8192) {
        int n = list[ii];
        const float* zp = z + (size_t)(n >> 12) * CHW_ + (n & 4095);
#pragma unroll
        for (int j = 0; j < 4; j++)
            zd[w][l * 4 + j] = (double)zp[(size_t)(l * 4 + j) * HW_];
        asm volatile("s_waitcnt lgkmcnt(0)" ::: "memory");
        double acc[16];
#pragma unroll
        for (int a = 0; a < 16; a++) acc[a] = 0.0;
        for (int c = 0; c < 256; c++) {
            double zc = zd[w][c];
            const float* cp = cbT + (size_t)c * K_ + l * 4;
#pragma unroll
            for (int it = 0; it < 4; it++) {
                float4 cv = *(const float4*)(cp + it * 256);
                acc[it * 4 + 0] += zc * (double)cv.x;
                acc[it * 4 + 1] += zc * (double)cv.y;
                acc[it * 4 + 2] += zc * (double)cv.z;
                acc[it * 4 + 3] += zc * (double)cv.w;
            }
        }
        float szv = sz[n];
        float best = FLT_BIG; int bidx = K_;
#pragma unroll
        for (int it = 0; it < 4; it++)
#pragma unroll
            for (int s = 0; s < 4; s++) {
                int k = it * 256 + l * 4 + s;
                float dotf = (float)acc[it * 4 + s];
                float dq = (szv + sc[k]) - 2.0f * dotf;
                if (dq < best || (dq == best && k < bidx)) { best = dq; bidx = k; }
            }
#pragma unroll
        for (int off = 32; off > 0; off >>= 1) {
            float ob = __shfl_xor(best, off, 64);
            int   oj = __shfl_xor(bidx, off, 64);
            if (ob < best || (ob == best && oj < bidx)) { best = ob; bidx = oj; }
        }
        if (l == 0) { fidx[n] = bidx; out_idx[n] = (float)bidx; }
        asm volatile("s_waitcnt lgkmcnt(0)" ::: "memory");
    }
}

// ---------------------------------------------------------------------------
// Gather zq -> NCHW output + loss partials (PASSED r2/r4)
// ---------------------------------------------------------------------------
__global__ void output_kernel(const float* __restrict__ z, const float* __restrict__ cb,
                              const int* __restrict__ fidx,
                              float* __restrict__ out0, double* __restrict__ partials) {
    __shared__ double red[256];
    int t = threadIdx.x;
    int blk = blockIdx.x;
    int n0 = blk * 64;
    int batch = n0 >> 12, s0 = n0 & 4095;
    const float* zbase = z + (size_t)batch * CHW_ + s0;
    float* obase = out0 + (size_t)batch * CHW_ + s0;
    double sum = 0.0;
#pragma unroll 4
    for (int r = 0; r < 64; r++) {
        int f = r * 256 + t;
        int c = f >> 6, i = f & 63;
        int idx = fidx[n0 + i];
        float q  = cb[(size_t)idx * C_ + c];
        float zv = zbase[(size_t)c * HW_ + i];
        obase[(size_t)c * HW_ + i] = q;
        float d = q - zv;
        sum += (double)d * (double)d;
    }
    red[t] = sum;
    __syncthreads();
    for (int s = 128; s > 0; s >>= 1) {
        if (t < s) red[t] += red[t + s];
        __syncthreads();
    }
    if (t == 0) partials[blk] = red[0];
}

__global__ void loss_kernel(const double* __restrict__ partials, float* __restrict__ out_loss) {
    __shared__ double red[256];
    int t = threadIdx.x;
    double s = 0.0;
    for (int r = t; r < 1024; r += 256) s += partials[r];
    red[t] = s;
    __syncthreads();
    for (int k = 128; k > 0; k >>= 1) {
        if (t < k) red[t] += red[t + k];
        __syncthreads();
    }
    if (t == 0) *out_loss = (float)(0.75 * red[0] / 16777216.0);
}

// ---------------------------------------------------------------------------
extern "C" void kernel_launch(void* const* d_in, const int* in_sizes, int n_in,
                              void* d_out, int out_size, void* d_ws, size_t ws_size,
                              hipStream_t stream) {
    const float* z  = (const float*)d_in[0];
    const float* cb = (const float*)d_in[1];

    float* out0     = (float*)d_out;
    float* out_idx  = out0 + (size_t)16777216;
    float* out_loss = out0 + (size_t)16842752;

    char* w = (char*)d_ws;
    double* partials = (double*)w;                       //       0 .. 8192
    float*  sc   = (float*)(w + 8192);                   //    8192 .. 12288
    float*  sz   = (float*)(w + 12288);                  //   12288 .. 274432
    float*  s1   = (float*)(w + 274432);
    float*  s2   = (float*)(w + 536576);
    int*    i1   = (int*)  (w + 798720);
    int*    fidx = (int*)  (w + 1060864);
    int*    count= (int*)  (w + 1323008);
    int*    list = (int*)  (w + 1323264);                // 256 KB
    unsigned short* cbh = (unsigned short*)(w + 1585408);// 512 KB
    float*  cbT  = (float*)(w + 2109952);                // 1 MB -> ends ~3.1 MB

    hipMemsetAsync(count, 0, 4, stream);
    sz_kernel    <<<256,  256, 0, stream>>>(z, sz);
    sc_kernel    <<<4,    256, 0, stream>>>(cb, sc);
    cbh_prep     <<<1024, 256, 0, stream>>>(cb, cbh);
    cbT_prep     <<<256, 1024, 0, stream>>>(cb, cbT);
    score_kernel <<<1024, 256, 0, stream>>>(z, cbh, sc, s1, s2, i1);
    flag_kernel  <<<256,  256, 0, stream>>>(s1, s2, i1, fidx, out_idx, list, count);
    refine_kernel<<<2048, 256, 0, stream>>>(z, cbT, sz, sc, list, count, fidx, out_idx);
    output_kernel<<<1024, 256, 0, stream>>>(z, cb, fidx, out0, partials);
    loss_kernel  <<<1,    256, 0, stream>>>(partials, out_loss);
}

// Round 7
// 317.004 us; speedup vs baseline: 1.0103x; 1.0103x over previous
//
#include <hip/hip_runtime.h>
#include <hip/hip_fp16.h>

#define B_    16
#define C_    256
#define HW_   4096
#define CHW_  1048576
#define N_    65536
#define K_    1024
#define FLT_BIG 3.402823466e38f
#define GAP_T  1.2e-4f   // ref fp32-quant floor 6.1e-5 + 6sigma fp16 score err ~3.1e-5 + key-pack 8e-6 + margin

typedef _Float16 half8 __attribute__((ext_vector_type(8)));
typedef float   float16 __attribute__((ext_vector_type(16)));

__device__ __forceinline__ unsigned umin_(unsigned a, unsigned b) { return a < b ? a : b; }
__device__ __forceinline__ unsigned umax_(unsigned a, unsigned b) { return a > b ? a : b; }

// ---------------------------------------------------------------------------
// s_z split into 16x-parallel partial pass + exact combine.
// Baseline sz_kernel was grid=256 (1 block/CU, latency-bound) reading 64 MB.
// szp: thread owns ONE (h,j) chain of pixel n: r = v(s=0)^2 then
//      r += v(s)^2 for s=1..15 sequentially -- identical association order
//      to baseline's r[j] chain (numpy pairwise, PASSED r2/r4).
// szc: combines the 16 partials in the baseline's exact tree:
//      blk[h] = ((r0+r1)+(r2+r3))+((r4+r5)+(r6+r7)); sz = blk0+blk1.
// Bit-exact vs baseline; 16x the parallelism (4096 blocks -> BW-bound).
// ---------------------------------------------------------------------------
__global__ void szp_kernel(const float* __restrict__ z, float* __restrict__ rp) {
#pragma clang fp contract(off)
    int hj = blockIdx.x >> 8;              // 0..15  (h = hj>>3, j = hj&7)
    int bx = blockIdx.x & 255;
    int n  = bx * 256 + threadIdx.x;
    int h = hj >> 3, j = hj & 7;
    const float* p = z + (size_t)(n >> 12) * CHW_ + (n & 4095)
                       + (size_t)(h * 128 + j) * HW_;
    float v = p[0];
    float r = v * v;
    for (int s = 1; s < 16; s++) {
        float u = p[(size_t)(s * 8) * HW_];
        r += u * u;
    }
    rp[(size_t)hj * N_ + n] = r;
}

__global__ void szc_kernel(const float* __restrict__ rp, float* __restrict__ sz) {
#pragma clang fp contract(off)
    int n = blockIdx.x * 256 + threadIdx.x;
    float blk[2];
    for (int h = 0; h < 2; h++) {
        const float* b = rp + (size_t)(h * 8) * N_ + n;
        float r0 = b[0 * N_], r1 = b[1 * N_], r2 = b[2 * N_], r3 = b[3 * N_];
        float r4 = b[4 * N_], r5 = b[5 * N_], r6 = b[6 * N_], r7 = b[7 * N_];
        blk[h] = ((r0 + r1) + (r2 + r3)) + ((r4 + r5) + (r6 + r7));
    }
    sz[n] = blk[0] + blk[1];
}

// ---------------------------------------------------------------------------
// s_c[k] numpy pairwise order (PASSED r2/r4)
// ---------------------------------------------------------------------------
__global__ void sc_kernel(const float* __restrict__ cb, float* __restrict__ sc) {
#pragma clang fp contract(off)
    int k = blockIdx.x * 256 + threadIdx.x;
    const float* p0 = cb + (size_t)k * C_;
    float blk[2];
    for (int h = 0; h < 2; h++) {
        const float* p = p0 + h * 128;
        float r[8];
#pragma unroll
        for (int j = 0; j < 8; j++) { float v = p[j]; r[j] = v * v; }
        for (int i = 8; i < 128; i += 8) {
#pragma unroll
            for (int j = 0; j < 8; j++) { float v = p[i + j]; r[j] += v * v; }
        }
        blk[h] = ((r[0] + r[1]) + (r[2] + r[3])) + ((r[4] + r[5]) + (r[6] + r[7]));
    }
    sc[k] = blk[0] + blk[1];
}

// ---------------------------------------------------------------------------
// Prep: codebook -> fp16 (x1024 exact scale, avoids fp16 denormal band),
// A-fragment image per K-step.  Element: (kk*1024 + k)*16 + h*8 + j
// with channel c = kk*16 + h*8 + j.  512 KB, L2-resident.
// ---------------------------------------------------------------------------
__global__ void cbh_prep(const float* __restrict__ cb, unsigned short* __restrict__ cbh) {
    int k = blockIdx.x, c = threadIdx.x;
    float v = cb[(size_t)k * C_ + c] * 1024.0f;
    __half hv = __float2half_rn(v);
    size_t F = ((size_t)(c >> 4) * 1024 + k) * 16 + ((c >> 3) & 1) * 8 + (c & 7);
    cbh[F] = __half_as_ushort(hv);
}

// Prep: cbT[c][k] = cb[k][c] fp32 (refine's coalesced per-lane-k loads)
__global__ void cbT_prep(const float* __restrict__ cb, float* __restrict__ cbT) {
    int c = blockIdx.x, k = threadIdx.x;
    cbT[(size_t)c * K_ + k] = cb[(size_t)k * C_ + c];
}

// ---------------------------------------------------------------------------
// fp16 MFMA score kernel.  Block = 64 pixels, 256 thr (4 waves).
// Wave w covers codes chunk*256 + w*64 + mt*32 + (l&31), 4 chunks of 256.
// A-frags from global (L2) with depth-2 register prefetch - no in-loop
// barriers.  z tile fp16 in LDS, XOR-swizzled (conflict-free b128 reads).
// Scores shifted +0.25 (positive => uint-monotone); packed key =
// (asuint(s') & ~127) | (chunk<<5)|(mt<<4)|r  -> branchless top-2 via
// u32 min/max, first-index ties automatic.
// C/D: col(pixel)=lane&31, row(code)=(r&3)+8*(r>>2)+4*(lane>>5) [HW-verified].
// NOTE: LDS deliberately 41984 B (3 blocks/CU).  All 40960-B (4 blocks/CU)
// variants failed idx verification 3-for-3 (r3/r4/r5) - do not retry
// without a mechanism.
// ---------------------------------------------------------------------------
__global__ __launch_bounds__(256, 4)
void score_kernel(const float* __restrict__ z, const unsigned short* __restrict__ cbh,
                  const float* __restrict__ sc,
                  float* __restrict__ s1o, float* __restrict__ s2o,
                  int* __restrict__ i1o) {
    __shared__ __align__(16) int zw[64 * 132];   // 64 px rows x 132 words (128 data + 4 pad), 33792 B
    __shared__ float scs[1024];                  // sc + 0.25, 4 KB
    __shared__ float ex[4 * 64 * 4];             // cross-wave merge, 4 KB

    int t = threadIdx.x;
    int w = t >> 6, l = t & 63;
    int n0 = blockIdx.x * 64;

    // stage shifted sc
    for (int i = t; i < 1024; i += 256) scs[i] = sc[i] + 0.25f;

    // stage z tile as packed fp16 pairs, XOR-swizzled 16B chunks.
    // thread (w,l): pixel px=l, channels [w*64, w*64+64)
    {
        int px = l;
        const float* zp = z + (size_t)(n0 >> 12) * CHW_ + (n0 & 4095) + px;
        int key = (px >> 3) & 3;
#pragma unroll 4
        for (int i = 0; i < 32; i++) {
            int widx = w * 32 + i;               // logical word in row [0,128)
            int c0 = widx * 2;
            float v0 = zp[(size_t)c0 * HW_];
            float v1 = zp[(size_t)(c0 + 1) * HW_];
            unsigned pk = (unsigned)__half_as_ushort(__float2half_rn(v0))
                        | ((unsigned)__half_as_ushort(__float2half_rn(v1)) << 16);
            int c16 = widx >> 2, rem = widx & 3;
            zw[px * 132 + (((c16 ^ key) << 2) | rem)] = pk;
        }
    }
    __syncthreads();

    unsigned b1[2] = { 0xFFFFFFFFu, 0xFFFFFFFFu };
    unsigned b2[2] = { 0xFFFFFFFFu, 0xFFFFFFFFu };

    // A-frag base (ushort index): code-in-chunk row = w*64 + mt*32 + (l&31)
    const unsigned short* ab = cbh + ((size_t)(w * 64 + (l & 31)) * 16 + (l >> 5) * 8);
    // step s (0..63): offset = (s&15)*16384 + (s>>4)*4096 ; mt stride 512
    short rowmap = (short)((l >> 5) << 2);       // +4*(lane>>5) in C/D rows
    half8 pf[2][2];
#pragma unroll
    for (int i = 0; i < 2; i++) {
        const unsigned short* s = ab + (i & 15) * 16384 + (i >> 4) * 4096;
        pf[i][0] = *(const half8*)(s);
        pf[i][1] = *(const half8*)(s + 512);
    }

    int bkey = ((l & 31) >> 3) & 3;
    int prow0 = (l & 31) * 132;

    for (int chunk = 0; chunk < 4; chunk++) {
        float16 acc[2][2];
#pragma unroll
        for (int mt = 0; mt < 2; mt++)
#pragma unroll
            for (int nt = 0; nt < 2; nt++)
#pragma unroll
                for (int r = 0; r < 16; r++) acc[mt][nt][r] = 0.f;

#pragma unroll
        for (int kk = 0; kk < 16; kk++) {
            int step = chunk * 16 + kk;
            int buf = step & 1;
            half8 a0 = pf[buf][0], a1 = pf[buf][1];
            int ns = step + 2; if (ns > 63) ns = 63;
            {
                const unsigned short* s = ab + (ns & 15) * 16384 + (ns >> 4) * 4096;
                pf[buf][0] = *(const half8*)(s);
                pf[buf][1] = *(const half8*)(s + 512);
            }
            half8 bz[2];
#pragma unroll
            for (int nt = 0; nt < 2; nt++) {
                int c16 = kk * 2 + (l >> 5);
                int word = (nt * 32 * 132 + prow0) + ((c16 ^ bkey) << 2);
                bz[nt] = *(const half8*)((const char*)zw + (size_t)word * 4);
            }
            acc[0][0] = __builtin_amdgcn_mfma_f32_32x32x16_f16(a0, bz[0], acc[0][0], 0, 0, 0);
            acc[0][1] = __builtin_amdgcn_mfma_f32_32x32x16_f16(a0, bz[1], acc[0][1], 0, 0, 0);
            acc[1][0] = __builtin_amdgcn_mfma_f32_32x32x16_f16(a1, bz[0], acc[1][0], 0, 0, 0);
            acc[1][1] = __builtin_amdgcn_mfma_f32_32x32x16_f16(a1, bz[1], acc[1][1], 0, 0, 0);
        }

        // fold into packed-key top-2 (s' = sc+0.25 - 2^-9*acc, positive)
#pragma unroll
        for (int mt = 0; mt < 2; mt++)
#pragma unroll
            for (int r = 0; r < 16; r++) {
                int scode = chunk * 256 + w * 64 + mt * 32
                          + (r & 3) + ((r >> 2) << 3) + rowmap;
                float sv = scs[scode];
                unsigned emb = (unsigned)((chunk << 5) | (mt << 4) | r);
#pragma unroll
                for (int nt = 0; nt < 2; nt++) {
                    float s = fmaf(-0.001953125f, acc[mt][nt][r], sv);
                    unsigned key = (__float_as_uint(s) & 0xFFFFFF80u) | emb;
                    b2[nt] = umin_(b2[nt], umax_(b1[nt], key));
                    b1[nt] = umin_(b1[nt], key);
                }
            }
    }

    // decode + lane-pair merge (l, l^32: same pixel, disjoint code rows)
#pragma unroll
    for (int nt = 0; nt < 2; nt++) {
        unsigned e1 = b1[nt] & 127u;
        float f1 = __uint_as_float(b1[nt] & 0xFFFFFF80u);
        float f2 = __uint_as_float(b2[nt] & 0xFFFFFF80u);
        int idx = (int)(e1 >> 5) * 256 + w * 64 + (int)((e1 >> 4) & 1) * 32
                + (int)(e1 & 3) + (int)(((e1 >> 2) & 3) << 3) + (int)rowmap;

        float of1 = __shfl_xor(f1, 32, 64);
        int   oi  = __shfl_xor(idx, 32, 64);
        float of2 = __shfl_xor(f2, 32, 64);
        if (of1 < f1 || (of1 == f1 && oi < idx)) {
            f2 = fminf(f1, of2); f1 = of1; idx = oi;
        } else {
            f2 = fminf(f2, of1);
        }

        if (l < 32) {
            int e = (w * 64 + nt * 32 + l) * 4;
            ex[e + 0] = f1;
            ex[e + 1] = f2;
            ((int*)ex)[e + 2] = idx;
        }
    }
    __syncthreads();
    if (t < 64) {
        float cb1 = FLT_BIG, cb2 = FLT_BIG; int cj1 = 0;
#pragma unroll
        for (int wv = 0; wv < 4; wv++) {
            int e = (wv * 64 + t) * 4;
            float nb1 = ex[e + 0];
            float nb2 = ex[e + 1];
            int   nj1 = ((int*)ex)[e + 2];
            if (nb1 < cb1 || (nb1 == cb1 && nj1 < cj1)) {
                cb2 = fminf(cb1, nb2); cb1 = nb1; cj1 = nj1;
            } else {
                cb2 = fminf(cb2, nb1);
            }
        }
        int n = n0 + t;
        s1o[n] = cb1; s2o[n] = cb2; i1o[n] = cj1;
    }
}

// ---------------------------------------------------------------------------
// Flag pass: commit clear winners; compact near-ties.
// ---------------------------------------------------------------------------
__global__ void flag_kernel(const float* __restrict__ s1, const float* __restrict__ s2,
                            const int* __restrict__ i1,
                            int* __restrict__ fidx, float* __restrict__ out_idx,
                            int* __restrict__ list, int* __restrict__ count) {
    int n = blockIdx.x * 256 + threadIdx.x;
    int j = i1[n];
    fidx[n] = j;
    out_idx[n] = (float)j;
    if (s2[n] - s1[n] < GAP_T) {
        int pos = atomicAdd(count, 1);
        list[pos] = n;
    }
}

// ---------------------------------------------------------------------------
// Exact refine (PASSED r4 semantics, unchanged except grid stride 8192):
// wave per flagged pixel, fp64 dot via cbT, then reference-quantized fp32:
//   dq = fp32( fp32(sz + sc[k]) - 2*fp32(dot) ), first-index argmin.
// Grid 2048 blocks -> 32 waves/CU -> L2 latency hidden.
// ---------------------------------------------------------------------------
__global__ void refine_kernel(const float* __restrict__ z, const float* __restrict__ cbT,
                              const float* __restrict__ sz, const float* __restrict__ sc,
                              const int* __restrict__ list, const int* __restrict__ count,
                              int* __restrict__ fidx, float* __restrict__ out_idx) {
    __shared__ double zd[4][256];
    int w = threadIdx.x >> 6, l = threadIdx.x & 63;
    int cnt = *count;
    if (cnt > 65536) cnt = 65536;
    for (int ii = blockIdx.x * 4 + w; ii < cnt; ii += 8192) {
        int n = list[ii];
        const float* zp = z + (size_t)(n >> 12) * CHW_ + (n & 4095);
#pragma unroll
        for (int j = 0; j < 4; j++)
            zd[w][l * 4 + j] = (double)zp[(size_t)(l * 4 + j) * HW_];
        asm volatile("s_waitcnt lgkmcnt(0)" ::: "memory");
        double acc[16];
#pragma unroll
        for (int a = 0; a < 16; a++) acc[a] = 0.0;
        for (int c = 0; c < 256; c++) {
            double zc = zd[w][c];
            const float* cp = cbT + (size_t)c * K_ + l * 4;
#pragma unroll
            for (int it = 0; it < 4; it++) {
                float4 cv = *(const float4*)(cp + it * 256);
                acc[it * 4 + 0] += zc * (double)cv.x;
                acc[it * 4 + 1] += zc * (double)cv.y;
                acc[it * 4 + 2] += zc * (double)cv.z;
                acc[it * 4 + 3] += zc * (double)cv.w;
            }
        }
        float szv = sz[n];
        float best = FLT_BIG; int bidx = K_;
#pragma unroll
        for (int it = 0; it < 4; it++)
#pragma unroll
            for (int s = 0; s < 4; s++) {
                int k = it * 256 + l * 4 + s;
                float dotf = (float)acc[it * 4 + s];
                float dq = (szv + sc[k]) - 2.0f * dotf;
                if (dq < best || (dq == best && k < bidx)) { best = dq; bidx = k; }
            }
#pragma unroll
        for (int off = 32; off > 0; off >>= 1) {
            float ob = __shfl_xor(best, off, 64);
            int   oj = __shfl_xor(bidx, off, 64);
            if (ob < best || (ob == best && oj < bidx)) { best = ob; bidx = oj; }
        }
        if (l == 0) { fidx[n] = bidx; out_idx[n] = (float)bidx; }
        asm volatile("s_waitcnt lgkmcnt(0)" ::: "memory");
    }
}

// ---------------------------------------------------------------------------
// Gather zq -> NCHW output + loss partials (PASSED r2/r4)
// ---------------------------------------------------------------------------
__global__ void output_kernel(const float* __restrict__ z, const float* __restrict__ cb,
                              const int* __restrict__ fidx,
                              float* __restrict__ out0, double* __restrict__ partials) {
    __shared__ double red[256];
    int t = threadIdx.x;
    int blk = blockIdx.x;
    int n0 = blk * 64;
    int batch = n0 >> 12, s0 = n0 & 4095;
    const float* zbase = z + (size_t)batch * CHW_ + s0;
    float* obase = out0 + (size_t)batch * CHW_ + s0;
    double sum = 0.0;
#pragma unroll 4
    for (int r = 0; r < 64; r++) {
        int f = r * 256 + t;
        int c = f >> 6, i = f & 63;
        int idx = fidx[n0 + i];
        float q  = cb[(size_t)idx * C_ + c];
        float zv = zbase[(size_t)c * HW_ + i];
        obase[(size_t)c * HW_ + i] = q;
        float d = q - zv;
        sum += (double)d * (double)d;
    }
    red[t] = sum;
    __syncthreads();
    for (int s = 128; s > 0; s >>= 1) {
        if (t < s) red[t] += red[t + s];
        __syncthreads();
    }
    if (t == 0) partials[blk] = red[0];
}

__global__ void loss_kernel(const double* __restrict__ partials, float* __restrict__ out_loss) {
    __shared__ double red[256];
    int t = threadIdx.x;
    double s = 0.0;
    for (int r = t; r < 1024; r += 256) s += partials[r];
    red[t] = s;
    __syncthreads();
    for (int k = 128; k > 0; k >>= 1) {
        if (t < k) red[t] += red[t + k];
        __syncthreads();
    }
    if (t == 0) *out_loss = (float)(0.75 * red[0] / 16777216.0);
}

// ---------------------------------------------------------------------------
extern "C" void kernel_launch(void* const* d_in, const int* in_sizes, int n_in,
                              void* d_out, int out_size, void* d_ws, size_t ws_size,
                              hipStream_t stream) {
    const float* z  = (const float*)d_in[0];
    const float* cb = (const float*)d_in[1];

    float* out0     = (float*)d_out;
    float* out_idx  = out0 + (size_t)16777216;
    float* out_loss = out0 + (size_t)16842752;

    char* w = (char*)d_ws;
    double* partials = (double*)w;                       //       0 .. 8192
    float*  sc   = (float*)(w + 8192);                   //    8192 .. 12288
    float*  sz   = (float*)(w + 12288);                  //   12288 .. 274432
    float*  s1   = (float*)(w + 274432);
    float*  s2   = (float*)(w + 536576);
    int*    i1   = (int*)  (w + 798720);
    int*    fidx = (int*)  (w + 1060864);
    int*    count= (int*)  (w + 1323008);
    int*    list = (int*)  (w + 1323264);                // 256 KB
    unsigned short* cbh = (unsigned short*)(w + 1585408);// 512 KB
    float*  cbT  = (float*)(w + 2109952);                // 1 MB -> ends 3158528
    float*  rp   = (float*)(w + 3158528);                // 4 MB sz partials -> ends 7352832

    hipMemsetAsync(count, 0, 4, stream);
    szp_kernel   <<<4096, 256, 0, stream>>>(z, rp);
    szc_kernel   <<<256,  256, 0, stream>>>(rp, sz);
    sc_kernel    <<<4,    256, 0, stream>>>(cb, sc);
    cbh_prep     <<<1024, 256, 0, stream>>>(cb, cbh);
    cbT_prep     <<<256, 1024, 0, stream>>>(cb, cbT);
    score_kernel <<<1024, 256, 0, stream>>>(z, cbh, sc, s1, s2, i1);
    flag_kernel  <<<256,  256, 0, stream>>>(s1, s2, i1, fidx, out_idx, list, count);
    refine_kernel<<<2048, 256, 0, stream>>>(z, cbT, sz, sc, list, count, fidx, out_idx);
    output_kernel<<<1024, 256, 0, stream>>>(z, cb, fidx, out0, partials);
    loss_kernel  <<<1,    256, 0, stream>>>(partials, out_loss);
}

// Round 8
// 280.122 us; speedup vs baseline: 1.1433x; 1.1317x over previous
//
#include <hip/hip_runtime.h>
#include <hip/hip_fp16.h>

#define B_    16
#define C_    256
#define HW_   4096
#define CHW_  1048576
#define N_    65536
#define K_    1024
#define FLT_BIG 3.402823466e38f
#define GAP_T  1.2e-4f   // ref fp32-quant floor 6.1e-5 + 6sigma fp16 score err ~3.1e-5 + key-pack 8e-6 + margin

typedef _Float16 half8 __attribute__((ext_vector_type(8)));
typedef float   float16 __attribute__((ext_vector_type(16)));

__device__ __forceinline__ unsigned umin_(unsigned a, unsigned b) { return a < b ? a : b; }
__device__ __forceinline__ unsigned umax_(unsigned a, unsigned b) { return a > b ? a : b; }

// ---------------------------------------------------------------------------
// s_z split into 16x-parallel partial pass + exact combine (PASSED r7).
// szp: thread owns ONE (h,j) chain of pixel n, sequential i-order.
// szc: combines partials in baseline's exact tree. Bit-exact vs r2/r4 sz.
// ---------------------------------------------------------------------------
__global__ void szp_kernel(const float* __restrict__ z, float* __restrict__ rp) {
#pragma clang fp contract(off)
    int hj = blockIdx.x >> 8;              // 0..15  (h = hj>>3, j = hj&7)
    int bx = blockIdx.x & 255;
    int n  = bx * 256 + threadIdx.x;
    int h = hj >> 3, j = hj & 7;
    const float* p = z + (size_t)(n >> 12) * CHW_ + (n & 4095)
                       + (size_t)(h * 128 + j) * HW_;
    float v = p[0];
    float r = v * v;
    for (int s = 1; s < 16; s++) {
        float u = p[(size_t)(s * 8) * HW_];
        r += u * u;
    }
    rp[(size_t)hj * N_ + n] = r;
}

__global__ void szc_kernel(const float* __restrict__ rp, float* __restrict__ sz) {
#pragma clang fp contract(off)
    int n = blockIdx.x * 256 + threadIdx.x;
    float blk[2];
    for (int h = 0; h < 2; h++) {
        const float* b = rp + (size_t)(h * 8) * N_ + n;
        float r0 = b[0 * N_], r1 = b[1 * N_], r2 = b[2 * N_], r3 = b[3 * N_];
        float r4 = b[4 * N_], r5 = b[5 * N_], r6 = b[6 * N_], r7 = b[7 * N_];
        blk[h] = ((r0 + r1) + (r2 + r3)) + ((r4 + r5) + (r6 + r7));
    }
    sz[n] = blk[0] + blk[1];
}

// ---------------------------------------------------------------------------
// s_c[k] numpy pairwise order (PASSED r2/r4)
// ---------------------------------------------------------------------------
__global__ void sc_kernel(const float* __restrict__ cb, float* __restrict__ sc) {
#pragma clang fp contract(off)
    int k = blockIdx.x * 256 + threadIdx.x;
    const float* p0 = cb + (size_t)k * C_;
    float blk[2];
    for (int h = 0; h < 2; h++) {
        const float* p = p0 + h * 128;
        float r[8];
#pragma unroll
        for (int j = 0; j < 8; j++) { float v = p[j]; r[j] = v * v; }
        for (int i = 8; i < 128; i += 8) {
#pragma unroll
            for (int j = 0; j < 8; j++) { float v = p[i + j]; r[j] += v * v; }
        }
        blk[h] = ((r[0] + r[1]) + (r[2] + r[3])) + ((r[4] + r[5]) + (r[6] + r[7]));
    }
    sc[k] = blk[0] + blk[1];
}

// ---------------------------------------------------------------------------
// Prep: codebook -> fp16 (x1024 exact scale, avoids fp16 denormal band),
// A-fragment image per K-step.  512 KB, L2-resident.
// ---------------------------------------------------------------------------
__global__ void cbh_prep(const float* __restrict__ cb, unsigned short* __restrict__ cbh) {
    int k = blockIdx.x, c = threadIdx.x;
    float v = cb[(size_t)k * C_ + c] * 1024.0f;
    __half hv = __float2half_rn(v);
    size_t F = ((size_t)(c >> 4) * 1024 + k) * 16 + ((c >> 3) & 1) * 8 + (c & 7);
    cbh[F] = __half_as_ushort(hv);
}

// Prep: cbT[c][k] = cb[k][c] fp32 (refine's coalesced per-lane-k loads)
__global__ void cbT_prep(const float* __restrict__ cb, float* __restrict__ cbT) {
    int c = blockIdx.x, k = threadIdx.x;
    cbT[(size_t)c * K_ + k] = cb[(size_t)k * C_ + c];
}

// ---------------------------------------------------------------------------
// fp16 MFMA score kernel.  Block = 64 pixels, 256 thr (4 waves).
// (structure PASSED r6/r7; see r6 notes)
// NOTE: LDS deliberately 41984 B (3 blocks/CU).  All 40960-B (4 blocks/CU)
// variants failed idx verification 3-for-3 (r3/r4/r5) with identical
// arithmetic - do not retry without a mechanism.
// NEW r8: s_setprio(1/0) around the MFMA cluster (T5) - waves here run
// barrier-free and de-phased (attn-like regime, m191 +4-7%), L2 A-prefetch
// under-covers by ~100cy; scheduling hint only, no numeric change.
// ---------------------------------------------------------------------------
__global__ __launch_bounds__(256, 4)
void score_kernel(const float* __restrict__ z, const unsigned short* __restrict__ cbh,
                  const float* __restrict__ sc,
                  float* __restrict__ s1o, float* __restrict__ s2o,
                  int* __restrict__ i1o) {
    __shared__ __align__(16) int zw[64 * 132];   // 64 px rows x 132 words (128 data + 4 pad), 33792 B
    __shared__ float scs[1024];                  // sc + 0.25, 4 KB
    __shared__ float ex[4 * 64 * 4];             // cross-wave merge, 4 KB

    int t = threadIdx.x;
    int w = t >> 6, l = t & 63;
    int n0 = blockIdx.x * 64;

    // stage shifted sc
    for (int i = t; i < 1024; i += 256) scs[i] = sc[i] + 0.25f;

    // stage z tile as packed fp16 pairs, XOR-swizzled 16B chunks.
    {
        int px = l;
        const float* zp = z + (size_t)(n0 >> 12) * CHW_ + (n0 & 4095) + px;
        int key = (px >> 3) & 3;
#pragma unroll 4
        for (int i = 0; i < 32; i++) {
            int widx = w * 32 + i;               // logical word in row [0,128)
            int c0 = widx * 2;
            float v0 = zp[(size_t)c0 * HW_];
            float v1 = zp[(size_t)(c0 + 1) * HW_];
            unsigned pk = (unsigned)__half_as_ushort(__float2half_rn(v0))
                        | ((unsigned)__half_as_ushort(__float2half_rn(v1)) << 16);
            int c16 = widx >> 2, rem = widx & 3;
            zw[px * 132 + (((c16 ^ key) << 2) | rem)] = pk;
        }
    }
    __syncthreads();

    unsigned b1[2] = { 0xFFFFFFFFu, 0xFFFFFFFFu };
    unsigned b2[2] = { 0xFFFFFFFFu, 0xFFFFFFFFu };

    const unsigned short* ab = cbh + ((size_t)(w * 64 + (l & 31)) * 16 + (l >> 5) * 8);
    short rowmap = (short)((l >> 5) << 2);       // +4*(lane>>5) in C/D rows
    half8 pf[2][2];
#pragma unroll
    for (int i = 0; i < 2; i++) {
        const unsigned short* s = ab + (i & 15) * 16384 + (i >> 4) * 4096;
        pf[i][0] = *(const half8*)(s);
        pf[i][1] = *(const half8*)(s + 512);
    }

    int bkey = ((l & 31) >> 3) & 3;
    int prow0 = (l & 31) * 132;

    for (int chunk = 0; chunk < 4; chunk++) {
        float16 acc[2][2];
#pragma unroll
        for (int mt = 0; mt < 2; mt++)
#pragma unroll
            for (int nt = 0; nt < 2; nt++)
#pragma unroll
                for (int r = 0; r < 16; r++) acc[mt][nt][r] = 0.f;

#pragma unroll
        for (int kk = 0; kk < 16; kk++) {
            int step = chunk * 16 + kk;
            int buf = step & 1;
            half8 a0 = pf[buf][0], a1 = pf[buf][1];
            int ns = step + 2; if (ns > 63) ns = 63;
            {
                const unsigned short* s = ab + (ns & 15) * 16384 + (ns >> 4) * 4096;
                pf[buf][0] = *(const half8*)(s);
                pf[buf][1] = *(const half8*)(s + 512);
            }
            half8 bz[2];
#pragma unroll
            for (int nt = 0; nt < 2; nt++) {
                int c16 = kk * 2 + (l >> 5);
                int word = (nt * 32 * 132 + prow0) + ((c16 ^ bkey) << 2);
                bz[nt] = *(const half8*)((const char*)zw + (size_t)word * 4);
            }
            __builtin_amdgcn_s_setprio(1);
            acc[0][0] = __builtin_amdgcn_mfma_f32_32x32x16_f16(a0, bz[0], acc[0][0], 0, 0, 0);
            acc[0][1] = __builtin_amdgcn_mfma_f32_32x32x16_f16(a0, bz[1], acc[0][1], 0, 0, 0);
            acc[1][0] = __builtin_amdgcn_mfma_f32_32x32x16_f16(a1, bz[0], acc[1][0], 0, 0, 0);
            acc[1][1] = __builtin_amdgcn_mfma_f32_32x32x16_f16(a1, bz[1], acc[1][1], 0, 0, 0);
            __builtin_amdgcn_s_setprio(0);
        }

        // fold into packed-key top-2 (s' = sc+0.25 - 2^-9*acc, positive)
#pragma unroll
        for (int mt = 0; mt < 2; mt++)
#pragma unroll
            for (int r = 0; r < 16; r++) {
                int scode = chunk * 256 + w * 64 + mt * 32
                          + (r & 3) + ((r >> 2) << 3) + rowmap;
                float sv = scs[scode];
                unsigned emb = (unsigned)((chunk << 5) | (mt << 4) | r);
#pragma unroll
                for (int nt = 0; nt < 2; nt++) {
                    float s = fmaf(-0.001953125f, acc[mt][nt][r], sv);
                    unsigned key = (__float_as_uint(s) & 0xFFFFFF80u) | emb;
                    b2[nt] = umin_(b2[nt], umax_(b1[nt], key));
                    b1[nt] = umin_(b1[nt], key);
                }
            }
    }

    // decode + lane-pair merge (l, l^32: same pixel, disjoint code rows)
#pragma unroll
    for (int nt = 0; nt < 2; nt++) {
        unsigned e1 = b1[nt] & 127u;
        float f1 = __uint_as_float(b1[nt] & 0xFFFFFF80u);
        float f2 = __uint_as_float(b2[nt] & 0xFFFFFF80u);
        int idx = (int)(e1 >> 5) * 256 + w * 64 + (int)((e1 >> 4) & 1) * 32
                + (int)(e1 & 3) + (int)(((e1 >> 2) & 3) << 3) + (int)rowmap;

        float of1 = __shfl_xor(f1, 32, 64);
        int   oi  = __shfl_xor(idx, 32, 64);
        float of2 = __shfl_xor(f2, 32, 64);
        if (of1 < f1 || (of1 == f1 && oi < idx)) {
            f2 = fminf(f1, of2); f1 = of1; idx = oi;
        } else {
            f2 = fminf(f2, of1);
        }

        if (l < 32) {
            int e = (w * 64 + nt * 32 + l) * 4;
            ex[e + 0] = f1;
            ex[e + 1] = f2;
            ((int*)ex)[e + 2] = idx;
        }
    }
    __syncthreads();
    if (t < 64) {
        float cb1 = FLT_BIG, cb2 = FLT_BIG; int cj1 = 0;
#pragma unroll
        for (int wv = 0; wv < 4; wv++) {
            int e = (wv * 64 + t) * 4;
            float nb1 = ex[e + 0];
            float nb2 = ex[e + 1];
            int   nj1 = ((int*)ex)[e + 2];
            if (nb1 < cb1 || (nb1 == cb1 && nj1 < cj1)) {
                cb2 = fminf(cb1, nb2); cb1 = nb1; cj1 = nj1;
            } else {
                cb2 = fminf(cb2, nb1);
            }
        }
        int n = n0 + t;
        s1o[n] = cb1; s2o[n] = cb2; i1o[n] = cj1;
    }
}

// ---------------------------------------------------------------------------
// Flag pass: commit clear winners; compact near-ties.
// ---------------------------------------------------------------------------
__global__ void flag_kernel(const float* __restrict__ s1, const float* __restrict__ s2,
                            const int* __restrict__ i1,
                            int* __restrict__ fidx, float* __restrict__ out_idx,
                            int* __restrict__ list, int* __restrict__ count) {
    int n = blockIdx.x * 256 + threadIdx.x;
    int j = i1[n];
    fidx[n] = j;
    out_idx[n] = (float)j;
    if (s2[n] - s1[n] < GAP_T) {
        int pos = atomicAdd(count, 1);
        list[pos] = n;
    }
}

// ---------------------------------------------------------------------------
// Exact refine (PASSED r4 semantics): wave per flagged pixel, fp64 dot via
// cbT, then reference-quantized fp32 argmin.
// ---------------------------------------------------------------------------
__global__ void refine_kernel(const float* __restrict__ z, const float* __restrict__ cbT,
                              const float* __restrict__ sz, const float* __restrict__ sc,
                              const int* __restrict__ list, const int* __restrict__ count,
                              int* __restrict__ fidx, float* __restrict__ out_idx) {
    __shared__ double zd[4][256];
    int w = threadIdx.x >> 6, l = threadIdx.x & 63;
    int cnt = *count;
    if (cnt > 65536) cnt = 65536;
    for (int ii = blockIdx.x * 4 + w; ii < cnt; ii += 8192) {
        int n = list[ii];
        const float* zp = z + (size_t)(n >> 12) * CHW_ + (n & 4095);
#pragma unroll
        for (int j = 0; j < 4; j++)
            zd[w][l * 4 + j] = (double)zp[(size_t)(l * 4 + j) * HW_];
        asm volatile("s_waitcnt lgkmcnt(0)" ::: "memory");
        double acc[16];
#pragma unroll
        for (int a = 0; a < 16; a++) acc[a] = 0.0;
        for (int c = 0; c < 256; c++) {
            double zc = zd[w][c];
            const float* cp = cbT + (size_t)c * K_ + l * 4;
#pragma unroll
            for (int it = 0; it < 4; it++) {
                float4 cv = *(const float4*)(cp + it * 256);
                acc[it * 4 + 0] += zc * (double)cv.x;
                acc[it * 4 + 1] += zc * (double)cv.y;
                acc[it * 4 + 2] += zc * (double)cv.z;
                acc[it * 4 + 3] += zc * (double)cv.w;
            }
        }
        float szv = sz[n];
        float best = FLT_BIG; int bidx = K_;
#pragma unroll
        for (int it = 0; it < 4; it++)
#pragma unroll
            for (int s = 0; s < 4; s++) {
                int k = it * 256 + l * 4 + s;
                float dotf = (float)acc[it * 4 + s];
                float dq = (szv + sc[k]) - 2.0f * dotf;
                if (dq < best || (dq == best && k < bidx)) { best = dq; bidx = k; }
            }
#pragma unroll
        for (int off = 32; off > 0; off >>= 1) {
            float ob = __shfl_xor(best, off, 64);
            int   oj = __shfl_xor(bidx, off, 64);
            if (ob < best || (ob == best && oj < bidx)) { best = ob; bidx = oj; }
        }
        if (l == 0) { fidx[n] = bidx; out_idx[n] = (float)bidx; }
        asm volatile("s_waitcnt lgkmcnt(0)" ::: "memory");
    }
}

// ---------------------------------------------------------------------------
// Gather zq -> NCHW output + loss partials.
// r8 rewrite: float4 everywhere (was all-scalar 4B/lane + 64-line gather).
// Thread owns 4 consecutive pixels x 4 channels per pass; idx staged in LDS;
// cb row pointers hoisted.  Values bit-identical (exact copies of cb rows);
// loss partial reassociates in f64 only (~1e-13, far under threshold).
// ---------------------------------------------------------------------------
__global__ void output_kernel(const float* __restrict__ z, const float* __restrict__ cb,
                              const int* __restrict__ fidx,
                              float* __restrict__ out0, double* __restrict__ partials) {
    __shared__ int sidx[64];
    __shared__ double red[256];
    int t = threadIdx.x;
    int blk = blockIdx.x;
    int n0 = blk * 64;
    if (t < 64) sidx[t] = fidx[n0 + t];
    __syncthreads();
    int batch = n0 >> 12, s0 = n0 & 4095;
    const float* zbase = z + (size_t)batch * CHW_ + s0;
    float* obase = out0 + (size_t)batch * CHW_ + s0;
    int ig = (t & 15) * 4;                 // 4 consecutive pixels
    int cg = (t >> 4) * 4;                 // 4 consecutive channels (in 64-chunk)
    const float* r0 = cb + (size_t)sidx[ig + 0] * C_;
    const float* r1 = cb + (size_t)sidx[ig + 1] * C_;
    const float* r2 = cb + (size_t)sidx[ig + 2] * C_;
    const float* r3 = cb + (size_t)sidx[ig + 3] * C_;
    double sum = 0.0;
#pragma unroll
    for (int pass = 0; pass < 4; pass++) {
        int c0 = pass * 64 + cg;
        float4 q0 = *(const float4*)(r0 + c0);
        float4 q1 = *(const float4*)(r1 + c0);
        float4 q2 = *(const float4*)(r2 + c0);
        float4 q3 = *(const float4*)(r3 + c0);
        float a0[4] = { q0.x, q0.y, q0.z, q0.w };
        float a1[4] = { q1.x, q1.y, q1.z, q1.w };
        float a2[4] = { q2.x, q2.y, q2.z, q2.w };
        float a3[4] = { q3.x, q3.y, q3.z, q3.w };
#pragma unroll
        for (int j = 0; j < 4; j++) {
            size_t off = (size_t)(c0 + j) * HW_ + ig;
            float4 zv = *(const float4*)(zbase + off);
            float4 qq;
            qq.x = a0[j]; qq.y = a1[j]; qq.z = a2[j]; qq.w = a3[j];
            *(float4*)(obase + off) = qq;
            float d0 = qq.x - zv.x, d1 = qq.y - zv.y;
            float d2 = qq.z - zv.z, d3 = qq.w - zv.w;
            sum += (double)d0 * (double)d0;
            sum += (double)d1 * (double)d1;
            sum += (double)d2 * (double)d2;
            sum += (double)d3 * (double)d3;
        }
    }
    red[t] = sum;
    __syncthreads();
    for (int s = 128; s > 0; s >>= 1) {
        if (t < s) red[t] += red[t + s];
        __syncthreads();
    }
    if (t == 0) partials[blk] = red[0];
}

__global__ void loss_kernel(const double* __restrict__ partials, float* __restrict__ out_loss) {
    __shared__ double red[256];
    int t = threadIdx.x;
    double s = 0.0;
    for (int r = t; r < 1024; r += 256) s += partials[r];
    red[t] = s;
    __syncthreads();
    for (int k = 128; k > 0; k >>= 1) {
        if (t < k) red[t] += red[t + k];
        __syncthreads();
    }
    if (t == 0) *out_loss = (float)(0.75 * red[0] / 16777216.0);
}

// ---------------------------------------------------------------------------
extern "C" void kernel_launch(void* const* d_in, const int* in_sizes, int n_in,
                              void* d_out, int out_size, void* d_ws, size_t ws_size,
                              hipStream_t stream) {
    const float* z  = (const float*)d_in[0];
    const float* cb = (const float*)d_in[1];

    float* out0     = (float*)d_out;
    float* out_idx  = out0 + (size_t)16777216;
    float* out_loss = out0 + (size_t)16842752;

    char* w = (char*)d_ws;
    double* partials = (double*)w;                       //       0 .. 8192
    float*  sc   = (float*)(w + 8192);                   //    8192 .. 12288
    float*  sz   = (float*)(w + 12288);                  //   12288 .. 274432
    float*  s1   = (float*)(w + 274432);
    float*  s2   = (float*)(w + 536576);
    int*    i1   = (int*)  (w + 798720);
    int*    fidx = (int*)  (w + 1060864);
    int*    count= (int*)  (w + 1323008);
    int*    list = (int*)  (w + 1323264);                // 256 KB
    unsigned short* cbh = (unsigned short*)(w + 1585408);// 512 KB
    float*  cbT  = (float*)(w + 2109952);                // 1 MB -> ends 3158528
    float*  rp   = (float*)(w + 3158528);                // 4 MB sz partials -> ends 7352832

    hipMemsetAsync(count, 0, 4, stream);
    szp_kernel   <<<4096, 256, 0, stream>>>(z, rp);
    szc_kernel   <<<256,  256, 0, stream>>>(rp, sz);
    sc_kernel    <<<4,    256, 0, stream>>>(cb, sc);
    cbh_prep     <<<1024, 256, 0, stream>>>(cb, cbh);
    cbT_prep     <<<256, 1024, 0, stream>>>(cb, cbT);
    score_kernel <<<1024, 256, 0, stream>>>(z, cbh, sc, s1, s2, i1);
    flag_kernel  <<<256,  256, 0, stream>>>(s1, s2, i1, fidx, out_idx, list, count);
    refine_kernel<<<2048, 256, 0, stream>>>(z, cbT, sz, sc, list, count, fidx, out_idx);
    output_kernel<<<1024, 256, 0, stream>>>(z, cb, fidx, out0, partials);
    loss_kernel  <<<1,    256, 0, stream>>>(partials, out_loss);
}